// Round 4
// baseline (282.099 us; speedup 1.0000x reference)
//
#include <hip/hip_runtime.h>

#define N_NODES 50000
#define N_EDGES 600000
#define N_PAD 50048        // N rounded up to 64 (mlp tiles)
#define IN_CH 64
#define HID 128
#define N_GRAPHS 64
#define CAP 64             // per-node edge-slot capacity (max degree ~28 for this input)
#define CAP_SHIFT 6

typedef __attribute__((ext_vector_type(8))) short bf16x8;
typedef __attribute__((ext_vector_type(4))) float f32x4;

// ---- bf16 helpers (manual, RNE) ----
__device__ __forceinline__ float bf2f(unsigned short u) {
    union { unsigned int i; float f; } v; v.i = ((unsigned int)u) << 16; return v.f;
}
__device__ __forceinline__ unsigned short f2bf(float f) {
    union { float f; unsigned int i; } v; v.f = f;
    unsigned int u = v.i;
    return (unsigned short)((u + 0x7FFFu + ((u >> 16) & 1u)) >> 16);
}

// 8B edge record: x = src(u16) | a0(bf16)<<16 ; y = a1(bf16) | a2(bf16)<<16

// ===========================================================================
// prep kernel (1 dispatch): zero deg+psum, 4 weight transposes, AND x->bf16.
// ===========================================================================
__global__ void prep_kernel(const float* __restrict__ x,
                            const float* __restrict__ w1a, const float* __restrict__ w1b,
                            const float* __restrict__ w2a, const float* __restrict__ w2b,
                            unsigned short* __restrict__ xbf,
                            unsigned short* __restrict__ waT1, unsigned short* __restrict__ wbT1,
                            unsigned short* __restrict__ waT2, unsigned short* __restrict__ wbT2,
                            int* __restrict__ deg, float* __restrict__ psum) {
    int i = blockIdx.x * blockDim.x + threadIdx.x;
    if (i < N_NODES * IN_CH) xbf[i] = f2bf(x[i]);
    if (i < N_NODES) deg[i] = 0;
    if (i < N_GRAPHS * HID) psum[i] = 0.f;
    if (i < IN_CH * HID) {               // w1a is [64,128]
        int k = i / HID, n = i % HID;
        waT1[n * IN_CH + k] = f2bf(w1a[i]);
    }
    if (i < HID * HID) {                 // the three [128,128] weights
        int k = i / HID, n = i % HID;
        wbT1[n * HID + k] = f2bf(w1b[i]);
        waT2[n * HID + k] = f2bf(w2a[i]);
        wbT2[n * HID + k] = f2bf(w2b[i]);
    }
}

// ===========================================================================
// Single-pass edge build: 1 edge/thread, fixed-capacity buckets.
// ===========================================================================
__global__ void build_kernel(const int* __restrict__ ei,
                             const float* __restrict__ ea,
                             int* __restrict__ deg,
                             uint2* __restrict__ edata) {
    int i = blockIdx.x * blockDim.x + threadIdx.x;
    if (i >= N_EDGES) return;
    int s = ei[i];
    int d = ei[N_EDGES + i];
    float a0 = ea[3 * (size_t)i], a1 = ea[3 * (size_t)i + 1], a2 = ea[3 * (size_t)i + 2];
    int p = atomicAdd(&deg[d], 1);
    if (p < CAP)
        edata[((size_t)d << CAP_SHIFT) + p] =
            make_uint2((unsigned)s | ((unsigned)f2bf(a0) << 16),
                       (unsigned)f2bf(a1) | ((unsigned)f2bf(a2) << 16));
}

// ===========================================================================
// FUSED gather + MFMA MLP (R4). Block = 256 threads = 4 waves, 64 nodes.
// Each wave gathers ITS OWN 16 MFMA rows into an LDS sg-tile (gather bodies
// verbatim from the R1/R3-proven kernels), then runs the R12-proven MFMA
// phases. sOut ALIASES sgTile+sHid (both dead after the aA/aB fragment
// loads); one __syncthreads guards the alias. LDS ~34.8KB -> 4 blocks/CU.
// Deletes the sg global round-trip (51MB) and 2 dispatches; gather latency
// of some waves overlaps MFMA of others on the same CU.
// ===========================================================================
template <int K, bool POOL>
__global__ __launch_bounds__(256)
void gine_fused_kernel(const unsigned short* __restrict__ xin,  // bf16 [N, K]
                       const uint2* __restrict__ edata,
                       const int* __restrict__ deg,
                       const float* __restrict__ elw,   // [3, K]
                       const float* __restrict__ elb,   // [K]
                       const unsigned short* __restrict__ waT,  // bf16 [HID, K]
                       const float* __restrict__ ba,
                       const unsigned short* __restrict__ wbT,  // bf16 [HID, HID]
                       const float* __restrict__ bb,
                       void* __restrict__ outv,                 // bf16 h or f32 psum
                       const int* __restrict__ batch) {
    constexpr int SSTR = K + 8;        // sg-tile row stride, shorts
    constexpr int HSTR = 136;          // shorts
    constexpr int OSTR = HID + 4;      // f32
    constexpr int SG_B  = 64 * SSTR * 2;
    constexpr int HID_B = 4 * 16 * HSTR * 2;
    constexpr int OUT_B = 64 * OSTR * 4;
    constexpr int TOT_B = (SG_B + HID_B > OUT_B) ? (SG_B + HID_B) : OUT_B;
    __shared__ __align__(16) char lds[TOT_B];
    unsigned short* sgT  = (unsigned short*)lds;           // [64][SSTR]
    unsigned short* sHid = (unsigned short*)(lds + SG_B);  // [4][16*HSTR]
    float* sOut = (float*)lds;                             // [64][OSTR], aliases

    const int t = threadIdx.x;
    const int w = t >> 6, l = t & 63;
    const int i16 = l & 15, q = l >> 4;
    const int blk0 = blockIdx.x * 64;
    const int lrow0 = w * 16;          // this wave's local row base
    const int node0 = blk0 + lrow0;

    // ================= gather phase (own 16 rows -> sgT) =================
    if constexpr (K == IN_CH) {
        // lane l = channel; one node at a time (R1 gather64 body)
        const float w0 = elw[l], w1 = elw[K + l], w2 = elw[2 * K + l], eb = elb[l];
        auto term = [&](uint2 e, unsigned short row) -> float {
            float ev = bf2f((unsigned short)(e.x >> 16)) * w0 +
                       bf2f((unsigned short)(e.y & 0xFFFF)) * w1 +
                       bf2f((unsigned short)(e.y >> 16)) * w2 + eb;
            float m = bf2f(row) + ev;
            return m > 0.f ? m : 0.f;
        };
        for (int i = 0; i < 16; i++) {
            int node = node0 + i;
            if (node >= N_NODES) break;   // pad rows: LDS stays stale, discarded
            float acc = bf2f(xin[(size_t)node * K + l]);
            int dn = deg[node]; if (dn > CAP) dn = CAP;
            int j = node << CAP_SHIFT; const int je = j + dn;
            for (; j + 8 <= je; j += 8) {
                uint2 e0 = edata[j],     e1 = edata[j + 1], e2 = edata[j + 2], e3 = edata[j + 3];
                uint2 e4 = edata[j + 4], e5 = edata[j + 5], e6 = edata[j + 6], e7 = edata[j + 7];
                unsigned short r0 = xin[(size_t)(e0.x & 0xFFFF) * K + l];
                unsigned short r1 = xin[(size_t)(e1.x & 0xFFFF) * K + l];
                unsigned short r2 = xin[(size_t)(e2.x & 0xFFFF) * K + l];
                unsigned short r3 = xin[(size_t)(e3.x & 0xFFFF) * K + l];
                unsigned short r4 = xin[(size_t)(e4.x & 0xFFFF) * K + l];
                unsigned short r5 = xin[(size_t)(e5.x & 0xFFFF) * K + l];
                unsigned short r6 = xin[(size_t)(e6.x & 0xFFFF) * K + l];
                unsigned short r7 = xin[(size_t)(e7.x & 0xFFFF) * K + l];
                acc += term(e0, r0) + term(e1, r1) + term(e2, r2) + term(e3, r3)
                     + term(e4, r4) + term(e5, r5) + term(e6, r6) + term(e7, r7);
            }
            for (; j + 4 <= je; j += 4) {
                uint2 e0 = edata[j], e1 = edata[j + 1], e2 = edata[j + 2], e3 = edata[j + 3];
                unsigned short r0 = xin[(size_t)(e0.x & 0xFFFF) * K + l];
                unsigned short r1 = xin[(size_t)(e1.x & 0xFFFF) * K + l];
                unsigned short r2 = xin[(size_t)(e2.x & 0xFFFF) * K + l];
                unsigned short r3 = xin[(size_t)(e3.x & 0xFFFF) * K + l];
                acc += term(e0, r0) + term(e1, r1) + term(e2, r2) + term(e3, r3);
            }
            for (; j < je; j++) {
                uint2 e0 = edata[j];
                acc += term(e0, xin[(size_t)(e0.x & 0xFFFF) * K + l]);
            }
            sgT[(lrow0 + i) * SSTR + l] = f2bf(acc);
        }
    } else {
        // lane l = packed channel pair (2l, 2l+1); paired-lockstep (R1 body)
        const unsigned* x32 = (const unsigned*)xin;     // row = 64 uints
        unsigned* sgT32 = (unsigned*)sgT;
        constexpr int S32 = SSTR / 2;
        const int c0 = 2 * l;
        const float w00 = elw[c0],           w01 = elw[c0 + 1];
        const float w10 = elw[HID + c0],     w11 = elw[HID + c0 + 1];
        const float w20 = elw[2 * HID + c0], w21 = elw[2 * HID + c0 + 1];
        const float eb0 = elb[c0],           eb1 = elb[c0 + 1];

        auto term2 = [&](uint2 e, unsigned r, float& p0, float& p1) {
            float A0 = bf2f((unsigned short)(e.x >> 16));
            float A1 = bf2f((unsigned short)(e.y & 0xFFFF));
            float A2 = bf2f((unsigned short)(e.y >> 16));
            float ev0 = A0 * w00 + A1 * w10 + A2 * w20 + eb0;
            float ev1 = A0 * w01 + A1 * w11 + A2 * w21 + eb1;
            float m0 = bf2f((unsigned short)(r & 0xFFFF)) + ev0;
            float m1 = bf2f((unsigned short)(r >> 16)) + ev1;
            p0 += m0 > 0.f ? m0 : 0.f;
            p1 += m1 > 0.f ? m1 : 0.f;
        };

        for (int p = 0; p < 8; p++) {
            int nA = node0 + 2 * p, nB = nA + 1;     // N_NODES even: nB valid iff nA valid
            if (nA >= N_NODES) break;
            unsigned svA = x32[(size_t)nA * 64 + l];
            unsigned svB = x32[(size_t)nB * 64 + l];
            float a0 = bf2f((unsigned short)(svA & 0xFFFF));
            float a1 = bf2f((unsigned short)(svA >> 16));
            float b0 = bf2f((unsigned short)(svB & 0xFFFF));
            float b1 = bf2f((unsigned short)(svB >> 16));

            int dA = deg[nA]; if (dA > CAP) dA = CAP;
            int dB = deg[nB]; if (dB > CAP) dB = CAP;
            int ja = nA << CAP_SHIFT; const int jaE = ja + dA;
            int jb = nB << CAP_SHIFT; const int jbE = jb + dB;
            while (ja + 4 <= jaE && jb + 4 <= jbE) {
                uint2 eA0 = edata[ja],     eA1 = edata[ja + 1], eA2 = edata[ja + 2], eA3 = edata[ja + 3];
                uint2 eB0 = edata[jb],     eB1 = edata[jb + 1], eB2 = edata[jb + 2], eB3 = edata[jb + 3];
                unsigned rA0 = x32[(size_t)(eA0.x & 0xFFFF) * 64 + l];
                unsigned rA1 = x32[(size_t)(eA1.x & 0xFFFF) * 64 + l];
                unsigned rA2 = x32[(size_t)(eA2.x & 0xFFFF) * 64 + l];
                unsigned rA3 = x32[(size_t)(eA3.x & 0xFFFF) * 64 + l];
                unsigned rB0 = x32[(size_t)(eB0.x & 0xFFFF) * 64 + l];
                unsigned rB1 = x32[(size_t)(eB1.x & 0xFFFF) * 64 + l];
                unsigned rB2 = x32[(size_t)(eB2.x & 0xFFFF) * 64 + l];
                unsigned rB3 = x32[(size_t)(eB3.x & 0xFFFF) * 64 + l];
                term2(eA0, rA0, a0, a1); term2(eA1, rA1, a0, a1);
                term2(eA2, rA2, a0, a1); term2(eA3, rA3, a0, a1);
                term2(eB0, rB0, b0, b1); term2(eB1, rB1, b0, b1);
                term2(eB2, rB2, b0, b1); term2(eB3, rB3, b0, b1);
                ja += 4; jb += 4;
            }
            for (; ja + 4 <= jaE; ja += 4) {
                uint2 e0 = edata[ja], e1 = edata[ja + 1], e2 = edata[ja + 2], e3 = edata[ja + 3];
                unsigned r0 = x32[(size_t)(e0.x & 0xFFFF) * 64 + l];
                unsigned r1 = x32[(size_t)(e1.x & 0xFFFF) * 64 + l];
                unsigned r2 = x32[(size_t)(e2.x & 0xFFFF) * 64 + l];
                unsigned r3 = x32[(size_t)(e3.x & 0xFFFF) * 64 + l];
                term2(e0, r0, a0, a1); term2(e1, r1, a0, a1);
                term2(e2, r2, a0, a1); term2(e3, r3, a0, a1);
            }
            for (; ja < jaE; ja++) {
                uint2 e0 = edata[ja];
                term2(e0, x32[(size_t)(e0.x & 0xFFFF) * 64 + l], a0, a1);
            }
            for (; jb + 4 <= jbE; jb += 4) {
                uint2 e0 = edata[jb], e1 = edata[jb + 1], e2 = edata[jb + 2], e3 = edata[jb + 3];
                unsigned r0 = x32[(size_t)(e0.x & 0xFFFF) * 64 + l];
                unsigned r1 = x32[(size_t)(e1.x & 0xFFFF) * 64 + l];
                unsigned r2 = x32[(size_t)(e2.x & 0xFFFF) * 64 + l];
                unsigned r3 = x32[(size_t)(e3.x & 0xFFFF) * 64 + l];
                term2(e0, r0, b0, b1); term2(e1, r1, b0, b1);
                term2(e2, r2, b0, b1); term2(e3, r3, b0, b1);
            }
            for (; jb < jbE; jb++) {
                uint2 e0 = edata[jb];
                term2(e0, x32[(size_t)(e0.x & 0xFFFF) * 64 + l], b0, b1);
            }
            sgT32[(lrow0 + 2 * p) * S32 + l]     = (unsigned)f2bf(a0) | ((unsigned)f2bf(a1) << 16);
            sgT32[(lrow0 + 2 * p + 1) * S32 + l] = (unsigned)f2bf(b0) | ((unsigned)f2bf(b1) << 16);
        }
    }
    // No barrier here: each wave MFMAs exactly the rows it gathered.

    // ---- layer A: [16 x K] @ waT -> relu -> own sHid buffer ----
    bf16x8 aA[K / 32];
    #pragma unroll
    for (int s = 0; s < K / 32; s++)
        aA[s] = *(const bf16x8*)&sgT[(size_t)(lrow0 + i16) * SSTR + s * 32 + q * 8];
    unsigned short* myHid = sHid + w * (16 * HSTR);
    #pragma unroll
    for (int ct = 0; ct < 8; ct++) {
        int col = ct * 16 + i16;
        float bv = ba[col];
        f32x4 acc = (f32x4){bv, bv, bv, bv};
        #pragma unroll
        for (int s = 0; s < K / 32; s++) {
            bf16x8 b = *(const bf16x8*)&waT[(size_t)col * K + s * 32 + q * 8];
            acc = __builtin_amdgcn_mfma_f32_16x16x32_bf16(aA[s], b, acc, 0, 0, 0);
        }
        #pragma unroll
        for (int r = 0; r < 4; r++) {
            float v = acc[r] > 0.f ? acc[r] : 0.f;
            myHid[(q * 4 + r) * HSTR + col] = f2bf(v);
        }
    }

    // ---- layer B: [16 x 128] @ wbT -> relu -> sOut (aliases sgT+sHid) ----
    bf16x8 aB[4];
    #pragma unroll
    for (int s = 0; s < 4; s++)
        aB[s] = *(const bf16x8*)&myHid[i16 * HSTR + s * 32 + q * 8];
    __syncthreads();   // ALL waves past their sgT/sHid reads -> safe to overwrite alias
    #pragma unroll
    for (int ct = 0; ct < 8; ct++) {
        int col = ct * 16 + i16;
        float bv = bb[col];
        f32x4 acc = (f32x4){bv, bv, bv, bv};
        #pragma unroll
        for (int s = 0; s < 4; s++) {
            bf16x8 b = *(const bf16x8*)&wbT[(size_t)col * HID + s * 32 + q * 8];
            acc = __builtin_amdgcn_mfma_f32_16x16x32_bf16(aB[s], b, acc, 0, 0, 0);
        }
        #pragma unroll
        for (int r = 0; r < 4; r++) {
            float v = acc[r] > 0.f ? acc[r] : 0.f;
            sOut[(lrow0 + q * 4 + r) * OSTR + col] = v;
        }
    }
    __syncthreads();

    // ---- epilogue (R12-proven) ----
    if (POOL) {
        if (t < HID) {
            float* psum = (float*)outv;
            float acc = 0.f;
            int curg = batch[blk0];
            for (int row = 0; row < 64; row++) {
                int node = blk0 + row;
                if (node >= N_NODES) break;
                int g = batch[node];
                if (g != curg) {
                    atomicAdd(&psum[curg * HID + t], acc);
                    acc = 0.f; curg = g;
                }
                acc += sOut[row * OSTR + t];
            }
            atomicAdd(&psum[curg * HID + t], acc);
        }
    } else {
        unsigned short* hout = (unsigned short*)outv;
        for (int idx = t; idx < 64 * 16; idx += 256) {
            int row = idx >> 4, ch = idx & 15;   // ch = 16B chunk (8 bf16)
            int node = blk0 + row;
            if (node < N_NODES) {
                float4 f0 = *(const float4*)&sOut[row * OSTR + ch * 8];
                float4 f1 = *(const float4*)&sOut[row * OSTR + ch * 8 + 4];
                uint4 u;
                u.x = (unsigned)f2bf(f0.x) | ((unsigned)f2bf(f0.y) << 16);
                u.y = (unsigned)f2bf(f0.z) | ((unsigned)f2bf(f0.w) << 16);
                u.z = (unsigned)f2bf(f1.x) | ((unsigned)f2bf(f1.y) << 16);
                u.w = (unsigned)f2bf(f1.z) | ((unsigned)f2bf(f1.w) << 16);
                *(uint4*)&hout[(size_t)node * HID + ch * 8] = u;
            }
        }
    }
}

// ---------------------------------------------------------------------------
// Pool mean: batch is SORTED -> count[g] by binary search (wave-uniform).
// ---------------------------------------------------------------------------
__global__ void pool_div_kernel(const float* __restrict__ sums,
                                const int* __restrict__ batch,
                                float* __restrict__ out) {
    int i = blockIdx.x * blockDim.x + threadIdx.x;
    if (i >= N_GRAPHS * HID) return;
    int g = i / HID;
    int lo = 0, hi = N_NODES;
    while (lo < hi) { int mid = (lo + hi) >> 1; if (batch[mid] < g) lo = mid + 1; else hi = mid; }
    int start = lo;
    lo = 0; hi = N_NODES;
    while (lo < hi) { int mid = (lo + hi) >> 1; if (batch[mid] <= g) lo = mid + 1; else hi = mid; }
    float c = (float)(lo - start);
    out[i] = sums[i] / (c > 1.0f ? c : 1.0f);
}

extern "C" void kernel_launch(void* const* d_in, const int* in_sizes, int n_in,
                              void* d_out, int out_size, void* d_ws, size_t ws_size,
                              hipStream_t stream) {
    const float* x    = (const float*)d_in[0];
    const int*   ei   = (const int*)d_in[1];
    const float* ea   = (const float*)d_in[2];
    const int*   batch= (const int*)d_in[3];
    const float* el1w = (const float*)d_in[4];
    const float* el1b = (const float*)d_in[5];
    const float* w1a  = (const float*)d_in[6];
    const float* b1a  = (const float*)d_in[7];
    const float* w1b  = (const float*)d_in[8];
    const float* b1b  = (const float*)d_in[9];
    const float* el2w = (const float*)d_in[10];
    const float* el2b = (const float*)d_in[11];
    const float* w2a  = (const float*)d_in[12];
    const float* b2a  = (const float*)d_in[13];
    const float* w2b  = (const float*)d_in[14];
    const float* b2b  = (const float*)d_in[15];
    float* out = (float*)d_out;

    // workspace layout (16B-aligned sections)
    uint2* edata    = (uint2*)d_ws;                        // [N*CAP] 8B records  25.6 MB
    float* psum     = (float*)(edata + (size_t)N_NODES * CAP);  // [G*HID] 8192 f32
    int*   deg      = (int*)(psum + N_GRAPHS * HID);       // [N]
    // ints after edata: 8192 + 50000 = 58192 (16B multiple)
    unsigned short* hbf  = (unsigned short*)((char*)psum + (size_t)58192 * 4);  // bf16 [N,HID]
    unsigned short* waT1 = hbf + (size_t)N_NODES * HID;  // bf16 [128, 64]
    unsigned short* wbT1 = waT1 + HID * IN_CH;           // bf16 [128, 128]
    unsigned short* waT2 = wbT1 + HID * HID;             // bf16 [128, 128]
    unsigned short* wbT2 = waT2 + HID * HID;             // bf16 [128, 128]
    unsigned short* xbf  = wbT2 + HID * HID;             // bf16 [N, 64]

    // ---- prep (1 dispatch): zero deg+psum, transpose weights, x->bf16 ----
    prep_kernel<<<(N_NODES * IN_CH) / 256, 256, 0, stream>>>(
        x, w1a, w1b, w2a, w2b, xbf, waT1, wbT1, waT2, wbT2, deg, psum);
    // ---- edge build: one dispatch, 1 edge/thread, fixed-capacity buckets ----
    build_kernel<<<(N_EDGES + 255) / 256, 256, 0, stream>>>(ei, ea, deg, edata);

    // ---- layer 1: fused gather64 + MFMA MLP -> hbf (bf16) ----
    gine_fused_kernel<IN_CH, false><<<N_PAD / 64, 256, 0, stream>>>(
        xbf, edata, deg, el1w, el1b, waT1, b1a, wbT1, b1b, hbf, nullptr);

    // ---- layer 2: fused gather128 + MFMA MLP + LDS pool -> psum ----
    gine_fused_kernel<HID, true><<<N_PAD / 64, 256, 0, stream>>>(
        hbf, edata, deg, el2w, el2b, waT2, b2a, wbT2, b2b, psum, batch);

    // ---- mean (count via binary search on sorted batch) ----
    pool_div_kernel<<<(N_GRAPHS * HID + 255) / 256, 256, 0, stream>>>(psum, batch, out);
}